// Round 9
// baseline (147.727 us; speedup 1.0000x reference)
//
#include <hip/hip_runtime.h>
#include <hip/hip_bf16.h>

#define B_N 8192
#define D_K 256
#define MARGIN 0.3f
#define NPAN 64     // 8192 / 128 panels

typedef float f32x4 __attribute__((ext_vector_type(4)));
typedef short s16x8 __attribute__((ext_vector_type(8)));

// async 16B global -> LDS (LDS dest = wave-uniform base + lane*16)
__device__ __forceinline__ void load_lds16(const unsigned short* g,
                                           unsigned short* l) {
    __builtin_amdgcn_global_load_lds(
        (const __attribute__((address_space(1))) unsigned int*)g,
        (__attribute__((address_space(3))) unsigned int*)l, 16, 0, 0);
}

// ---- kernel 1: bf16 round + norms OF ROUNDED VALUES + init ----------------
__global__ __launch_bounds__(256) void prep_kernel(const float* __restrict__ X,
        float* __restrict__ sq, unsigned short* __restrict__ Xp,
        float* __restrict__ acc2) {
    int row  = (blockIdx.x << 2) + (threadIdx.x >> 6);
    int lane = threadIdx.x & 63;
    const float4 v = reinterpret_cast<const float4*>(X + (size_t)row * D_K)[lane];

    float xs[4] = {v.x, v.y, v.z, v.w};
    ushort4 hv;
    unsigned short* hp = &hv.x;
    float s = 0.f;
    #pragma unroll
    for (int i = 0; i < 4; ++i) {
        __hip_bfloat16 h = __float2bfloat16(xs[i]);
        hp[i] = *reinterpret_cast<unsigned short*>(&h);
        float hf = __bfloat162float(h);
        s = fmaf(hf, hf, s);
    }
    *reinterpret_cast<ushort4*>(Xp + (size_t)row * D_K + lane * 4) = hv;

    #pragma unroll
    for (int o = 32; o > 0; o >>= 1) s += __shfl_down(s, o, 64);
    if (lane == 0) sq[row] = s;
    if (blockIdx.x == 0 && threadIdx.x == 0) {
        acc2[0] = 0.f; acc2[1] = 0.f;
        reinterpret_cast<unsigned*>(acc2)[2] = 0u;   // ticket counter
    }
}

// ---- kernel 2: R0 K-loop + atomic-free mining, LDS EXACTLY 32 KB ----------
#define BM 128
#define BN 128
// K-loop verbatim from the proven kernel (32 KB tiles, 2-phase per 64-k
// window, pre-swizzled global_load_lds, zero bank conflicts).
// Mining scratch (2 KB) is OVERLAID on the dead A-tile after a post-K-loop
// barrier -> total LDS = 32768 B exactly -> 5 blocks/CU (was 4 at 34.8 KB).
// Mining is atomic-free (R8 scheme): every part[q][i] has exactly one
// writer block; row side writes slot bx, col side slot by (diag col skipped).

__global__ __launch_bounds__(256, 5) void dist_kernel(
        const unsigned short* __restrict__ Xp,
        const int* __restrict__ tgt, const float* __restrict__ sq,
        float* __restrict__ part_ap, float* __restrict__ part_an) {
    __shared__ __align__(16) unsigned short smem[2][128 * 64];   // 32 KB total
    unsigned short* Atile = smem[0];
    unsigned short* Btile = smem[1];
    // overlay (valid after post-K-loop barrier): 2 KB of mining scratch
    float* rowap = reinterpret_cast<float*>(smem[0]);          // [128]
    float* rowan = rowap + 128;
    float* colap = rowap + 256;
    float* colan = rowap + 384;

    const int t    = threadIdx.x;
    const int lane = t & 63;
    const int wave = t >> 6;
    const int wrow = (wave >> 1) * 64;
    const int wcol = (wave & 1) * 64;
    const int fr   = lane & 15;
    const int quad = lane >> 4;
    const float INF = __int_as_float(0x7f800000);

    // triangular decode: blockIdx.x -> (bx, by), by <= bx
    int tt = blockIdx.x;
    int bx = (int)((sqrtf(8.f * (float)tt + 1.f) - 1.f) * 0.5f);
    while ((bx + 1) * (bx + 2) / 2 <= tt) ++bx;
    while (bx * (bx + 1) / 2 > tt) --bx;
    int by = tt - bx * (bx + 1) / 2;
    const int bm = by * BM;   // bm <= bn
    const int bn = bx * BN;

    // staging geometry: thread's 4 units per operand
    const unsigned short* ag[4];
    const unsigned short* bg[4];
    unsigned short* al[4];
    unsigned short* bl[4];
    #pragma unroll
    for (int j = 0; j < 4; ++j) {
        int g = wave * 64 + j * 256 + lane;   // 0..1023
        int r = g >> 3, s0 = g & 7;
        int u = s0 ^ (r & 7);
        ag[j] = Xp + (size_t)(bm + r) * D_K + u * 8;
        bg[j] = Xp + (size_t)(bn + r) * D_K + u * 8;
        al[j] = Atile + g * 8;                // wave base + lane*16B
        bl[j] = Btile + g * 8;
    }

    f32x4 acc[4][4];
    #pragma unroll
    for (int i = 0; i < 4; ++i)
        #pragma unroll
        for (int j = 0; j < 4; ++j) acc[i][j] = (f32x4){0.f, 0.f, 0.f, 0.f};

    #pragma unroll 1
    for (int win = 0; win < 4; ++win) {   // K = 64 per window
        __syncthreads();                  // prior fragment reads complete
        const int wo = win * 64;
        #pragma unroll
        for (int j = 0; j < 4; ++j) {
            load_lds16(ag[j] + wo, al[j]);
            load_lds16(bg[j] + wo, bl[j]);
        }
        __syncthreads();                  // staging drained

        s16x8 a[4][2], b[4][2];
        #pragma unroll
        for (int mi = 0; mi < 4; ++mi) {
            int rb = (wrow + mi * 16 + fr) * 64;
            #pragma unroll
            for (int h = 0; h < 2; ++h) {
                int s = (h * 4 + quad) ^ (fr & 7);
                a[mi][h] = *reinterpret_cast<const s16x8*>(&Atile[rb + s * 8]);
            }
        }
        #pragma unroll
        for (int ni = 0; ni < 4; ++ni) {
            int rb = (wcol + ni * 16 + fr) * 64;
            #pragma unroll
            for (int h = 0; h < 2; ++h) {
                int s = (h * 4 + quad) ^ (fr & 7);
                b[ni][h] = *reinterpret_cast<const s16x8*>(&Btile[rb + s * 8]);
            }
        }
        #pragma unroll
        for (int mi = 0; mi < 4; ++mi)
            #pragma unroll
            for (int ni = 0; ni < 4; ++ni) {
                acc[mi][ni] = __builtin_amdgcn_mfma_f32_16x16x32_bf16(
                    a[mi][0], b[ni][0], acc[mi][ni], 0, 0, 0);
                acc[mi][ni] = __builtin_amdgcn_mfma_f32_16x16x32_bf16(
                    a[mi][1], b[ni][1], acc[mi][ni], 0, 0, 0);
            }
    }

    __syncthreads();   // last window's tile reads done -> overlay is safe

    // -------- epilogue: dist + mining, NO ATOMICS --------------------------
    int   ct[4]; float csq[4];
    #pragma unroll
    for (int ni = 0; ni < 4; ++ni) {
        int c = bn + wcol + ni * 16 + fr;
        ct[ni] = tgt[c]; csq[ni] = sq[c];
    }
    float cap[4], can[4];
    #pragma unroll
    for (int ni = 0; ni < 4; ++ni) { cap[ni] = -INF; can[ni] = INF; }

    float rapv[16], ranv[16];
    #pragma unroll
    for (int mi = 0; mi < 4; ++mi) {
        #pragma unroll
        for (int reg = 0; reg < 4; ++reg) {
            int rl = wrow + mi * 16 + quad * 4 + reg;
            int rt = tgt[bm + rl]; float rsq = sq[bm + rl];
            float rap = -INF, ran = INF;
            #pragma unroll
            for (int ni = 0; ni < 4; ++ni) {
                float d = rsq + csq[ni] - 2.f * acc[mi][ni][reg];
                bool pos = (rt == ct[ni]);
                if (pos) { rap = fmaxf(rap, d); cap[ni] = fmaxf(cap[ni], d); }
                else     { ran = fminf(ran, d); can[ni] = fminf(can[ni], d); }
            }
            #pragma unroll
            for (int o = 1; o < 16; o <<= 1) {
                rap = fmaxf(rap, __shfl_xor(rap, o, 64));
                ran = fminf(ran, __shfl_xor(ran, o, 64));
            }
            rapv[mi * 4 + reg] = rap;
            ranv[mi * 4 + reg] = ran;
            if ((wave & 1) == 0 && fr == 0) {   // waves 0,2: deposit partials
                rowap[rl] = rap; rowan[rl] = ran;
            }
        }
    }

    // col partial: reduce across quads within wave
    #pragma unroll
    for (int ni = 0; ni < 4; ++ni) {
        #pragma unroll
        for (int o = 16; o < 64; o <<= 1) {
            cap[ni] = fmaxf(cap[ni], __shfl_xor(cap[ni], o, 64));
            can[ni] = fminf(can[ni], __shfl_xor(can[ni], o, 64));
        }
    }
    if (wave < 2 && lane < 16) {                // waves 0,1: deposit partials
        #pragma unroll
        for (int ni = 0; ni < 4; ++ni) {
            int c = wcol + ni * 16 + lane;
            colap[c] = cap[ni]; colan[c] = can[ni];
        }
    }

    __syncthreads();   // partials visible

    if (wave & 1) {                             // waves 1,3: finalize rows
        #pragma unroll
        for (int mi = 0; mi < 4; ++mi)
            #pragma unroll
            for (int reg = 0; reg < 4; ++reg) {
                int rl = wrow + mi * 16 + quad * 4 + reg;
                if (fr == 0) {
                    part_ap[(size_t)bx * B_N + bm + rl] =
                        fmaxf(rapv[mi * 4 + reg], rowap[rl]);
                    part_an[(size_t)bx * B_N + bm + rl] =
                        fminf(ranv[mi * 4 + reg], rowan[rl]);
                }
            }
    }
    if (wave >= 2 && bx != by && lane < 16) {   // waves 2,3: finalize cols
        #pragma unroll
        for (int ni = 0; ni < 4; ++ni) {
            int c = wcol + ni * 16 + lane;
            part_ap[(size_t)by * B_N + bn + c] = fmaxf(cap[ni], colap[c]);
            part_an[(size_t)by * B_N + bn + c] = fminf(can[ni], colan[c]);
        }
    }
}

// ---- kernel 3: high-MLP reduce of 64 slots/row + loss/prec + finalize -----
// 128 blocks x 256 threads = 4 threads per row; each thread reduces 16 slots
// with fully-unrolled independent loads (32 in flight) -> latency hidden.
__global__ __launch_bounds__(256) void final_kernel(
        const float* __restrict__ part_ap, const float* __restrict__ part_an,
        float* __restrict__ acc2, float* __restrict__ out) {
    __shared__ float s_sum[4], s_cnt[4];
    int gid = blockIdx.x * 256 + threadIdx.x;   // 0..32767
    int i   = gid >> 2;                          // row 0..8191
    int qg  = gid & 3;                           // q-group 0..3
    const float* pa = part_ap + (size_t)(qg * 16) * B_N + i;
    const float* pn = part_an + (size_t)(qg * 16) * B_N + i;
    float ap = pa[0];
    float an = pn[0];
    #pragma unroll
    for (int k = 1; k < 16; ++k) {
        ap = fmaxf(ap, pa[(size_t)k * B_N]);
        an = fminf(an, pn[(size_t)k * B_N]);
    }
    // combine the 4 q-groups of this row (adjacent lanes)
    #pragma unroll
    for (int o = 1; o < 4; o <<= 1) {
        ap = fmaxf(ap, __shfl_xor(ap, o, 64));
        an = fminf(an, __shfl_xor(an, o, 64));
    }
    float sum = 0.f, cnt = 0.f;
    if (qg == 0) {
        float v = ap - an + MARGIN;
        sum = v > 0.f ? v : 0.f;
        cnt = an > ap ? 1.f : 0.f;
    }
    #pragma unroll
    for (int o = 32; o > 0; o >>= 1) {
        sum += __shfl_down(sum, o, 64);
        cnt += __shfl_down(cnt, o, 64);
    }
    int wave = threadIdx.x >> 6, lane = threadIdx.x & 63;
    if (lane == 0) { s_sum[wave] = sum; s_cnt[wave] = cnt; }
    __syncthreads();
    if (threadIdx.x == 0) {
        float ts = 0.f, tc = 0.f;
        #pragma unroll
        for (int w = 0; w < 4; ++w) { ts += s_sum[w]; tc += s_cnt[w]; }
        atomicAdd(&acc2[0], ts);
        atomicAdd(&acc2[1], tc);
        __threadfence();
        unsigned ticket = atomicAdd(reinterpret_cast<unsigned*>(acc2) + 2, 1u);
        if (ticket == gridDim.x - 1) {
            float fs = atomicAdd(&acc2[0], 0.f);
            float fc = atomicAdd(&acc2[1], 0.f);
            out[0] = fs / (float)B_N;
            out[1] = fc / (float)B_N;
        }
    }
}

extern "C" void kernel_launch(void* const* d_in, const int* in_sizes, int n_in,
                              void* d_out, int out_size, void* d_ws, size_t ws_size,
                              hipStream_t stream) {
    const float* X   = (const float*)d_in[0];
    const int*   tgt = (const int*)d_in[1];

    char* ws = (char*)d_ws;
    float*          sq      = (float*)ws;                        // 32 KB
    float*          acc2    = (float*)(ws + 32768);              // 16 B
    float*          part_ap = (float*)(ws + 65536);              // 2 MB
    float*          part_an = (float*)(ws + 65536 + 2097152);    // 2 MB
    unsigned short* Xp      = (unsigned short*)(ws + 65536 + 4194304); // 4 MB

    float* out = (float*)d_out;

    prep_kernel<<<B_N / 4, 256, 0, stream>>>(X, sq, Xp, acc2);
    dist_kernel<<<(64 * 65) / 2, 256, 0, stream>>>(Xp, tgt, sq, part_ap, part_an);
    final_kernel<<<B_N / 64, 256, 0, stream>>>(part_ap, part_an, acc2, out);
}

// Round 10
// 113.277 us; speedup vs baseline: 1.3041x; 1.3041x over previous
//
#include <hip/hip_runtime.h>
#include <hip/hip_bf16.h>

#define B_N 8192
#define D_K 256
#define MARGIN 0.3f
#define NPAN 64     // 8192 / 128 panels

typedef float f32x4 __attribute__((ext_vector_type(4)));
typedef short s16x8 __attribute__((ext_vector_type(8)));

// async 16B global -> LDS (LDS dest = wave-uniform base + lane*16)
__device__ __forceinline__ void load_lds16(const unsigned short* g,
                                           unsigned short* l) {
    __builtin_amdgcn_global_load_lds(
        (const __attribute__((address_space(1))) unsigned int*)g,
        (__attribute__((address_space(3))) unsigned int*)l, 16, 0, 0);
}

// ---- kernel 1: bf16 round + norms OF ROUNDED VALUES + init ----------------
__global__ __launch_bounds__(256) void prep_kernel(const float* __restrict__ X,
        float* __restrict__ sq, unsigned short* __restrict__ Xp,
        float* __restrict__ acc2) {
    int row  = (blockIdx.x << 2) + (threadIdx.x >> 6);
    int lane = threadIdx.x & 63;
    const float4 v = reinterpret_cast<const float4*>(X + (size_t)row * D_K)[lane];

    float xs[4] = {v.x, v.y, v.z, v.w};
    ushort4 hv;
    unsigned short* hp = &hv.x;
    float s = 0.f;
    #pragma unroll
    for (int i = 0; i < 4; ++i) {
        __hip_bfloat16 h = __float2bfloat16(xs[i]);
        hp[i] = *reinterpret_cast<unsigned short*>(&h);
        float hf = __bfloat162float(h);
        s = fmaf(hf, hf, s);
    }
    *reinterpret_cast<ushort4*>(Xp + (size_t)row * D_K + lane * 4) = hv;

    #pragma unroll
    for (int o = 32; o > 0; o >>= 1) s += __shfl_down(s, o, 64);
    if (lane == 0) sq[row] = s;
    if (blockIdx.x == 0 && threadIdx.x == 0) {
        acc2[0] = 0.f; acc2[1] = 0.f;
        reinterpret_cast<unsigned*>(acc2)[2] = 0u;   // ticket counter
    }
}

// ---- kernel 2: R8 dist verbatim (measured 45.8 us) ------------------------
#define BM 128
#define BN 128
// K-loop: 32 KB tiles, 2-phase per 64-k window, pre-swizzled global_load_lds,
// zero bank conflicts. Mining: atomic-free; wave-pair partials combined via
// a separate 2 KB LDS scratch (NOT overlaid -- the (256,5)+overlay variant
// spilled accumulators to scratch: VGPR 48, +120 MB scratch traffic, 84 us).
// (256,4) keeps VGPR=64 arch + 64 AGPR with no spill. Every part[q][i] has
// exactly one writer block (row side slot bx, col side slot by, diag col
// skipped) -> no atomics, no init, no races.

__global__ __launch_bounds__(256, 4) void dist_kernel(
        const unsigned short* __restrict__ Xp,
        const int* __restrict__ tgt, const float* __restrict__ sq,
        float* __restrict__ part_ap, float* __restrict__ part_an) {
    __shared__ unsigned short Atile[128 * 64];   // 16 KB
    __shared__ unsigned short Btile[128 * 64];   // 16 KB
    __shared__ float rowap[128], rowan[128], colap[128], colan[128]; // 2 KB

    const int t    = threadIdx.x;
    const int lane = t & 63;
    const int wave = t >> 6;
    const int wrow = (wave >> 1) * 64;
    const int wcol = (wave & 1) * 64;
    const int fr   = lane & 15;
    const int quad = lane >> 4;
    const float INF = __int_as_float(0x7f800000);

    // triangular decode: blockIdx.x -> (bx, by), by <= bx
    int tt = blockIdx.x;
    int bx = (int)((sqrtf(8.f * (float)tt + 1.f) - 1.f) * 0.5f);
    while ((bx + 1) * (bx + 2) / 2 <= tt) ++bx;
    while (bx * (bx + 1) / 2 > tt) --bx;
    int by = tt - bx * (bx + 1) / 2;
    const int bm = by * BM;   // bm <= bn
    const int bn = bx * BN;

    // staging geometry: thread's 4 units per operand
    const unsigned short* ag[4];
    const unsigned short* bg[4];
    unsigned short* al[4];
    unsigned short* bl[4];
    #pragma unroll
    for (int j = 0; j < 4; ++j) {
        int g = wave * 64 + j * 256 + lane;   // 0..1023
        int r = g >> 3, s0 = g & 7;
        int u = s0 ^ (r & 7);
        ag[j] = Xp + (size_t)(bm + r) * D_K + u * 8;
        bg[j] = Xp + (size_t)(bn + r) * D_K + u * 8;
        al[j] = Atile + g * 8;                // wave base + lane*16B
        bl[j] = Btile + g * 8;
    }

    f32x4 acc[4][4];
    #pragma unroll
    for (int i = 0; i < 4; ++i)
        #pragma unroll
        for (int j = 0; j < 4; ++j) acc[i][j] = (f32x4){0.f, 0.f, 0.f, 0.f};

    #pragma unroll 1
    for (int win = 0; win < 4; ++win) {   // K = 64 per window
        __syncthreads();                  // prior fragment reads complete
        const int wo = win * 64;
        #pragma unroll
        for (int j = 0; j < 4; ++j) {
            load_lds16(ag[j] + wo, al[j]);
            load_lds16(bg[j] + wo, bl[j]);
        }
        __syncthreads();                  // staging drained

        s16x8 a[4][2], b[4][2];
        #pragma unroll
        for (int mi = 0; mi < 4; ++mi) {
            int rb = (wrow + mi * 16 + fr) * 64;
            #pragma unroll
            for (int h = 0; h < 2; ++h) {
                int s = (h * 4 + quad) ^ (fr & 7);
                a[mi][h] = *reinterpret_cast<const s16x8*>(&Atile[rb + s * 8]);
            }
        }
        #pragma unroll
        for (int ni = 0; ni < 4; ++ni) {
            int rb = (wcol + ni * 16 + fr) * 64;
            #pragma unroll
            for (int h = 0; h < 2; ++h) {
                int s = (h * 4 + quad) ^ (fr & 7);
                b[ni][h] = *reinterpret_cast<const s16x8*>(&Btile[rb + s * 8]);
            }
        }
        #pragma unroll
        for (int mi = 0; mi < 4; ++mi)
            #pragma unroll
            for (int ni = 0; ni < 4; ++ni) {
                acc[mi][ni] = __builtin_amdgcn_mfma_f32_16x16x32_bf16(
                    a[mi][0], b[ni][0], acc[mi][ni], 0, 0, 0);
                acc[mi][ni] = __builtin_amdgcn_mfma_f32_16x16x32_bf16(
                    a[mi][1], b[ni][1], acc[mi][ni], 0, 0, 0);
            }
    }

    // -------- epilogue: dist + mining, NO ATOMICS --------------------------
    int   ct[4]; float csq[4];
    #pragma unroll
    for (int ni = 0; ni < 4; ++ni) {
        int c = bn + wcol + ni * 16 + fr;
        ct[ni] = tgt[c]; csq[ni] = sq[c];
    }
    float cap[4], can[4];
    #pragma unroll
    for (int ni = 0; ni < 4; ++ni) { cap[ni] = -INF; can[ni] = INF; }

    float rapv[16], ranv[16];
    #pragma unroll
    for (int mi = 0; mi < 4; ++mi) {
        #pragma unroll
        for (int reg = 0; reg < 4; ++reg) {
            int rl = wrow + mi * 16 + quad * 4 + reg;
            int rt = tgt[bm + rl]; float rsq = sq[bm + rl];
            float rap = -INF, ran = INF;
            #pragma unroll
            for (int ni = 0; ni < 4; ++ni) {
                float d = rsq + csq[ni] - 2.f * acc[mi][ni][reg];
                bool pos = (rt == ct[ni]);
                if (pos) { rap = fmaxf(rap, d); cap[ni] = fmaxf(cap[ni], d); }
                else     { ran = fminf(ran, d); can[ni] = fminf(can[ni], d); }
            }
            #pragma unroll
            for (int o = 1; o < 16; o <<= 1) {
                rap = fmaxf(rap, __shfl_xor(rap, o, 64));
                ran = fminf(ran, __shfl_xor(ran, o, 64));
            }
            rapv[mi * 4 + reg] = rap;
            ranv[mi * 4 + reg] = ran;
            if ((wave & 1) == 0 && fr == 0) {   // waves 0,2: deposit partials
                rowap[rl] = rap; rowan[rl] = ran;
            }
        }
    }

    // col partial: reduce across quads within wave
    #pragma unroll
    for (int ni = 0; ni < 4; ++ni) {
        #pragma unroll
        for (int o = 16; o < 64; o <<= 1) {
            cap[ni] = fmaxf(cap[ni], __shfl_xor(cap[ni], o, 64));
            can[ni] = fminf(can[ni], __shfl_xor(can[ni], o, 64));
        }
    }
    if (wave < 2 && lane < 16) {                // waves 0,1: deposit partials
        #pragma unroll
        for (int ni = 0; ni < 4; ++ni) {
            int c = wcol + ni * 16 + lane;
            colap[c] = cap[ni]; colan[c] = can[ni];
        }
    }

    __syncthreads();   // partials visible

    if (wave & 1) {                             // waves 1,3: finalize rows
        #pragma unroll
        for (int mi = 0; mi < 4; ++mi)
            #pragma unroll
            for (int reg = 0; reg < 4; ++reg) {
                int rl = wrow + mi * 16 + quad * 4 + reg;
                if (fr == 0) {
                    part_ap[(size_t)bx * B_N + bm + rl] =
                        fmaxf(rapv[mi * 4 + reg], rowap[rl]);
                    part_an[(size_t)bx * B_N + bm + rl] =
                        fminf(ranv[mi * 4 + reg], rowan[rl]);
                }
            }
    }
    if (wave >= 2 && bx != by && lane < 16) {   // waves 2,3: finalize cols
        #pragma unroll
        for (int ni = 0; ni < 4; ++ni) {
            int c = wcol + ni * 16 + lane;
            part_ap[(size_t)by * B_N + bn + c] = fmaxf(cap[ni], colap[c]);
            part_an[(size_t)by * B_N + bn + c] = fminf(can[ni], colan[c]);
        }
    }
}

// ---- kernel 3: high-MLP reduce of 64 slots/row + loss/prec + finalize -----
// 128 blocks x 256 threads = 4 threads per row; each thread reduces 16 slots
// with fully-unrolled independent loads (32 in flight) -> latency hidden.
__global__ __launch_bounds__(256) void final_kernel(
        const float* __restrict__ part_ap, const float* __restrict__ part_an,
        float* __restrict__ acc2, float* __restrict__ out) {
    __shared__ float s_sum[4], s_cnt[4];
    int gid = blockIdx.x * 256 + threadIdx.x;   // 0..32767
    int i   = gid >> 2;                          // row 0..8191
    int qg  = gid & 3;                           // q-group 0..3
    const float* pa = part_ap + (size_t)(qg * 16) * B_N + i;
    const float* pn = part_an + (size_t)(qg * 16) * B_N + i;
    float ap = pa[0];
    float an = pn[0];
    #pragma unroll
    for (int k = 1; k < 16; ++k) {
        ap = fmaxf(ap, pa[(size_t)k * B_N]);
        an = fminf(an, pn[(size_t)k * B_N]);
    }
    // combine the 4 q-groups of this row (adjacent lanes)
    #pragma unroll
    for (int o = 1; o < 4; o <<= 1) {
        ap = fmaxf(ap, __shfl_xor(ap, o, 64));
        an = fminf(an, __shfl_xor(an, o, 64));
    }
    float sum = 0.f, cnt = 0.f;
    if (qg == 0) {
        float v = ap - an + MARGIN;
        sum = v > 0.f ? v : 0.f;
        cnt = an > ap ? 1.f : 0.f;
    }
    #pragma unroll
    for (int o = 32; o > 0; o >>= 1) {
        sum += __shfl_down(sum, o, 64);
        cnt += __shfl_down(cnt, o, 64);
    }
    int wave = threadIdx.x >> 6, lane = threadIdx.x & 63;
    if (lane == 0) { s_sum[wave] = sum; s_cnt[wave] = cnt; }
    __syncthreads();
    if (threadIdx.x == 0) {
        float ts = 0.f, tc = 0.f;
        #pragma unroll
        for (int w = 0; w < 4; ++w) { ts += s_sum[w]; tc += s_cnt[w]; }
        atomicAdd(&acc2[0], ts);
        atomicAdd(&acc2[1], tc);
        __threadfence();
        unsigned ticket = atomicAdd(reinterpret_cast<unsigned*>(acc2) + 2, 1u);
        if (ticket == gridDim.x - 1) {
            float fs = atomicAdd(&acc2[0], 0.f);
            float fc = atomicAdd(&acc2[1], 0.f);
            out[0] = fs / (float)B_N;
            out[1] = fc / (float)B_N;
        }
    }
}

extern "C" void kernel_launch(void* const* d_in, const int* in_sizes, int n_in,
                              void* d_out, int out_size, void* d_ws, size_t ws_size,
                              hipStream_t stream) {
    const float* X   = (const float*)d_in[0];
    const int*   tgt = (const int*)d_in[1];

    char* ws = (char*)d_ws;
    float*          sq      = (float*)ws;                        // 32 KB
    float*          acc2    = (float*)(ws + 32768);              // 16 B
    float*          part_ap = (float*)(ws + 65536);              // 2 MB
    float*          part_an = (float*)(ws + 65536 + 2097152);    // 2 MB
    unsigned short* Xp      = (unsigned short*)(ws + 65536 + 4194304); // 4 MB

    float* out = (float*)d_out;

    prep_kernel<<<B_N / 4, 256, 0, stream>>>(X, sq, Xp, acc2);
    dist_kernel<<<(64 * 65) / 2, 256, 0, stream>>>(Xp, tgt, sq, part_ap, part_an);
    final_kernel<<<B_N / 64, 256, 0, stream>>>(part_ap, part_an, acc2, out);
}

// Round 11
// 102.686 us; speedup vs baseline: 1.4386x; 1.1031x over previous
//
#include <hip/hip_runtime.h>
#include <hip/hip_bf16.h>

#define B_N 8192
#define D_K 256
#define MARGIN 0.3f
#define NPAN 64     // 8192 / 128 panels

typedef float f32x4 __attribute__((ext_vector_type(4)));
typedef short s16x8 __attribute__((ext_vector_type(8)));

// async 16B global -> LDS (LDS dest = wave-uniform base + lane*16)
__device__ __forceinline__ void load_lds16(const unsigned short* g,
                                           unsigned short* l) {
    __builtin_amdgcn_global_load_lds(
        (const __attribute__((address_space(1))) unsigned int*)g,
        (__attribute__((address_space(3))) unsigned int*)l, 16, 0, 0);
}

// ---- kernel 1: bf16 round + norms OF ROUNDED VALUES + init ----------------
__global__ __launch_bounds__(256) void prep_kernel(const float* __restrict__ X,
        float* __restrict__ sq, unsigned short* __restrict__ Xp,
        float* __restrict__ acc2) {
    int row  = (blockIdx.x << 2) + (threadIdx.x >> 6);
    int lane = threadIdx.x & 63;
    const float4 v = reinterpret_cast<const float4*>(X + (size_t)row * D_K)[lane];

    float xs[4] = {v.x, v.y, v.z, v.w};
    ushort4 hv;
    unsigned short* hp = &hv.x;
    float s = 0.f;
    #pragma unroll
    for (int i = 0; i < 4; ++i) {
        __hip_bfloat16 h = __float2bfloat16(xs[i]);
        hp[i] = *reinterpret_cast<unsigned short*>(&h);
        float hf = __bfloat162float(h);
        s = fmaf(hf, hf, s);
    }
    *reinterpret_cast<ushort4*>(Xp + (size_t)row * D_K + lane * 4) = hv;

    #pragma unroll
    for (int o = 32; o > 0; o >>= 1) s += __shfl_down(s, o, 64);
    if (lane == 0) sq[row] = s;
    if (blockIdx.x == 0 && threadIdx.x == 0) {
        acc2[0] = 0.f; acc2[1] = 0.f;
        reinterpret_cast<unsigned*>(acc2)[2] = 0u;   // ticket counter
    }
}

// ---- kernel 2: R10 K-loop + XCD swizzle + LDS scatter row-mining ----------
#define BM 128
#define BN 128
// K-loop: 32 KB tiles, 2-phase per 64-k window, pre-swizzled global_load_lds,
// zero bank conflicts (proven 45.4us at R10).
// NEW (a): XCD-aware blockIdx swizzle (2080%8==0 -> bijective (tt&7)*260 +
// (tt>>3)): consecutive tiles share panels within one XCD's 4MB L2; Xp is
// exactly 4MB so default round-robin thrashes it (FETCH 18.5MB vs 4.1 ideal).
// NEW (b): row mining via LDS scatter/reduce instead of 128 serial
// ds_swizzle chains: partials [128][33] f32 x2 OVERLAID on the dead tiles
// (union = 33792B; + 1KB col scratch = 34816B total, same as R10 -> still
// 4 blocks/CU at (256,4); R9's spill came from (256,5), not the overlay).
// Mining stays atomic-free: one writer per part[q][i].

__global__ __launch_bounds__(256, 4) void dist_kernel(
        const unsigned short* __restrict__ Xp,
        const int* __restrict__ tgt, const float* __restrict__ sq,
        float* __restrict__ part_ap, float* __restrict__ part_an) {
    __shared__ __align__(16) unsigned char uni[33792];   // tiles / scratch
    __shared__ float colap[128], colan[128];             // 1 KB, persistent
    unsigned short* Atile = reinterpret_cast<unsigned short*>(uni);
    unsigned short* Btile = reinterpret_cast<unsigned short*>(uni + 16384);
    float* APs = reinterpret_cast<float*>(uni);           // [128][33] overlay
    float* ANs = reinterpret_cast<float*>(uni + 16896);   // [128][33] overlay

    const int t    = threadIdx.x;
    const int lane = t & 63;
    const int wave = t >> 6;
    const int wrow = (wave >> 1) * 64;
    const int wcol = (wave & 1) * 64;
    const int fr   = lane & 15;
    const int quad = lane >> 4;
    const float INF = __int_as_float(0x7f800000);

    // XCD-aware swizzle, then triangular decode: tt -> (bx, by), by <= bx
    int tt = blockIdx.x;
    tt = (tt & 7) * 260 + (tt >> 3);          // 2080 = 8 * 260, bijective
    int bx = (int)((sqrtf(8.f * (float)tt + 1.f) - 1.f) * 0.5f);
    while ((bx + 1) * (bx + 2) / 2 <= tt) ++bx;
    while (bx * (bx + 1) / 2 > tt) --bx;
    int by = tt - bx * (bx + 1) / 2;
    const int bm = by * BM;   // bm <= bn
    const int bn = bx * BN;

    // staging geometry: thread's 4 units per operand
    const unsigned short* ag[4];
    const unsigned short* bg[4];
    unsigned short* al[4];
    unsigned short* bl[4];
    #pragma unroll
    for (int j = 0; j < 4; ++j) {
        int g = wave * 64 + j * 256 + lane;   // 0..1023
        int r = g >> 3, s0 = g & 7;
        int u = s0 ^ (r & 7);
        ag[j] = Xp + (size_t)(bm + r) * D_K + u * 8;
        bg[j] = Xp + (size_t)(bn + r) * D_K + u * 8;
        al[j] = Atile + g * 8;                // wave base + lane*16B
        bl[j] = Btile + g * 8;
    }

    f32x4 acc[4][4];
    #pragma unroll
    for (int i = 0; i < 4; ++i)
        #pragma unroll
        for (int j = 0; j < 4; ++j) acc[i][j] = (f32x4){0.f, 0.f, 0.f, 0.f};

    #pragma unroll 1
    for (int win = 0; win < 4; ++win) {   // K = 64 per window
        __syncthreads();                  // prior fragment reads complete
        const int wo = win * 64;
        #pragma unroll
        for (int j = 0; j < 4; ++j) {
            load_lds16(ag[j] + wo, al[j]);
            load_lds16(bg[j] + wo, bl[j]);
        }
        __syncthreads();                  // staging drained

        s16x8 a[4][2], b[4][2];
        #pragma unroll
        for (int mi = 0; mi < 4; ++mi) {
            int rb = (wrow + mi * 16 + fr) * 64;
            #pragma unroll
            for (int h = 0; h < 2; ++h) {
                int s = (h * 4 + quad) ^ (fr & 7);
                a[mi][h] = *reinterpret_cast<const s16x8*>(&Atile[rb + s * 8]);
            }
        }
        #pragma unroll
        for (int ni = 0; ni < 4; ++ni) {
            int rb = (wcol + ni * 16 + fr) * 64;
            #pragma unroll
            for (int h = 0; h < 2; ++h) {
                int s = (h * 4 + quad) ^ (fr & 7);
                b[ni][h] = *reinterpret_cast<const s16x8*>(&Btile[rb + s * 8]);
            }
        }
        #pragma unroll
        for (int mi = 0; mi < 4; ++mi)
            #pragma unroll
            for (int ni = 0; ni < 4; ++ni) {
                acc[mi][ni] = __builtin_amdgcn_mfma_f32_16x16x32_bf16(
                    a[mi][0], b[ni][0], acc[mi][ni], 0, 0, 0);
                acc[mi][ni] = __builtin_amdgcn_mfma_f32_16x16x32_bf16(
                    a[mi][1], b[ni][1], acc[mi][ni], 0, 0, 0);
            }
    }

    __syncthreads();   // last window's tile reads done -> overlay is safe

    // -------- epilogue: dist + scatter partials, NO ATOMICS ----------------
    int   ct[4]; float csq[4];
    #pragma unroll
    for (int ni = 0; ni < 4; ++ni) {
        int c = bn + wcol + ni * 16 + fr;
        ct[ni] = tgt[c]; csq[ni] = sq[c];
    }
    float cap[4], can[4];
    #pragma unroll
    for (int ni = 0; ni < 4; ++ni) { cap[ni] = -INF; can[ni] = INF; }

    const int mcol = (wave & 1) * 16 + fr;   // 0..31 partial slot per row
    #pragma unroll
    for (int mi = 0; mi < 4; ++mi) {
        #pragma unroll
        for (int reg = 0; reg < 4; ++reg) {
            int rl = wrow + mi * 16 + quad * 4 + reg;   // 0..127
            int rt = tgt[bm + rl]; float rsq = sq[bm + rl];
            float rap = -INF, ran = INF;
            #pragma unroll
            for (int ni = 0; ni < 4; ++ni) {
                float d = rsq + csq[ni] - 2.f * acc[mi][ni][reg];
                bool pos = (rt == ct[ni]);
                if (pos) { rap = fmaxf(rap, d); cap[ni] = fmaxf(cap[ni], d); }
                else     { ran = fminf(ran, d); can[ni] = fminf(can[ni], d); }
            }
            APs[rl * 33 + mcol] = rap;   // one writer per slot
            ANs[rl * 33 + mcol] = ran;
        }
    }

    // col partial: reduce across quads within wave (cheap: 16 shuffles)
    #pragma unroll
    for (int ni = 0; ni < 4; ++ni) {
        #pragma unroll
        for (int o = 16; o < 64; o <<= 1) {
            cap[ni] = fmaxf(cap[ni], __shfl_xor(cap[ni], o, 64));
            can[ni] = fminf(can[ni], __shfl_xor(can[ni], o, 64));
        }
    }
    if (wave < 2 && lane < 16) {                // waves 0,1: deposit partials
        #pragma unroll
        for (int ni = 0; ni < 4; ++ni) {
            int c = wcol + ni * 16 + lane;
            colap[c] = cap[ni]; colan[c] = can[ni];
        }
    }

    __syncthreads();   // scatter + col deposits visible

    // row mining: 256 threads, one (array, row) each; 2-way-free LDS reads
    {
        int arr = t >> 7;        // 0 = AP(max), 1 = AN(min)
        int row = t & 127;
        if (arr == 0) {
            const float* p = APs + row * 33;
            float v = p[0];
            #pragma unroll
            for (int j = 1; j < 32; ++j) v = fmaxf(v, p[j]);
            part_ap[(size_t)bx * B_N + bm + row] = v;
        } else {
            const float* p = ANs + row * 33;
            float v = p[0];
            #pragma unroll
            for (int j = 1; j < 32; ++j) v = fminf(v, p[j]);
            part_an[(size_t)bx * B_N + bm + row] = v;
        }
    }

    if (wave >= 2 && bx != by && lane < 16) {   // waves 2,3: finalize cols
        #pragma unroll
        for (int ni = 0; ni < 4; ++ni) {
            int c = wcol + ni * 16 + lane;
            part_ap[(size_t)by * B_N + bn + c] = fmaxf(cap[ni], colap[c]);
            part_an[(size_t)by * B_N + bn + c] = fminf(can[ni], colan[c]);
        }
    }
}

// ---- kernel 3: high-MLP reduce of 64 slots/row + loss/prec + finalize -----
__global__ __launch_bounds__(256) void final_kernel(
        const float* __restrict__ part_ap, const float* __restrict__ part_an,
        float* __restrict__ acc2, float* __restrict__ out) {
    __shared__ float s_sum[4], s_cnt[4];
    int gid = blockIdx.x * 256 + threadIdx.x;   // 0..32767
    int i   = gid >> 2;                          // row 0..8191
    int qg  = gid & 3;                           // q-group 0..3
    const float* pa = part_ap + (size_t)(qg * 16) * B_N + i;
    const float* pn = part_an + (size_t)(qg * 16) * B_N + i;
    float ap = pa[0];
    float an = pn[0];
    #pragma unroll
    for (int k = 1; k < 16; ++k) {
        ap = fmaxf(ap, pa[(size_t)k * B_N]);
        an = fminf(an, pn[(size_t)k * B_N]);
    }
    // combine the 4 q-groups of this row (adjacent lanes)
    #pragma unroll
    for (int o = 1; o < 4; o <<= 1) {
        ap = fmaxf(ap, __shfl_xor(ap, o, 64));
        an = fminf(an, __shfl_xor(an, o, 64));
    }
    float sum = 0.f, cnt = 0.f;
    if (qg == 0) {
        float v = ap - an + MARGIN;
        sum = v > 0.f ? v : 0.f;
        cnt = an > ap ? 1.f : 0.f;
    }
    #pragma unroll
    for (int o = 32; o > 0; o >>= 1) {
        sum += __shfl_down(sum, o, 64);
        cnt += __shfl_down(cnt, o, 64);
    }
    int wave = threadIdx.x >> 6, lane = threadIdx.x & 63;
    if (lane == 0) { s_sum[wave] = sum; s_cnt[wave] = cnt; }
    __syncthreads();
    if (threadIdx.x == 0) {
        float ts = 0.f, tc = 0.f;
        #pragma unroll
        for (int w = 0; w < 4; ++w) { ts += s_sum[w]; tc += s_cnt[w]; }
        atomicAdd(&acc2[0], ts);
        atomicAdd(&acc2[1], tc);
        __threadfence();
        unsigned ticket = atomicAdd(reinterpret_cast<unsigned*>(acc2) + 2, 1u);
        if (ticket == gridDim.x - 1) {
            float fs = atomicAdd(&acc2[0], 0.f);
            float fc = atomicAdd(&acc2[1], 0.f);
            out[0] = fs / (float)B_N;
            out[1] = fc / (float)B_N;
        }
    }
}

extern "C" void kernel_launch(void* const* d_in, const int* in_sizes, int n_in,
                              void* d_out, int out_size, void* d_ws, size_t ws_size,
                              hipStream_t stream) {
    const float* X   = (const float*)d_in[0];
    const int*   tgt = (const int*)d_in[1];

    char* ws = (char*)d_ws;
    float*          sq      = (float*)ws;                        // 32 KB
    float*          acc2    = (float*)(ws + 32768);              // 16 B
    float*          part_ap = (float*)(ws + 65536);              // 2 MB
    float*          part_an = (float*)(ws + 65536 + 2097152);    // 2 MB
    unsigned short* Xp      = (unsigned short*)(ws + 65536 + 4194304); // 4 MB

    float* out = (float*)d_out;

    prep_kernel<<<B_N / 4, 256, 0, stream>>>(X, sq, Xp, acc2);
    dist_kernel<<<(64 * 65) / 2, 256, 0, stream>>>(Xp, tgt, sq, part_ap, part_an);
    final_kernel<<<B_N / 64, 256, 0, stream>>>(part_ap, part_an, acc2, out);
}